// Round 2
// baseline (1088.098 us; speedup 1.0000x reference)
//
#include <hip/hip_runtime.h>
#include <math.h>

// TimestepNorm forward, prefix-sum reformulation:
//   c_t   = C0 + #valid<=t
//   M_t   = C0*pm + sum(valid*x)             -> mean = M/c
//   var_t = (V2 + sum(valid*x^2) - M_t^2/c_t)/c_t,  V2 = C0*(exp(plv)+pm^2)
//
// v3: single-pass fused kernel with decoupled lookback (rocPRIM-style).
// v2's 3-pass scheme read x twice and paid 3 dispatches; kernel-side time
// stayed ~150+ us. Here each block (chunk,b) loads its x slab into REGISTERS
// (CT=16 float4/lane), computes partials, publishes aggregate (agent-scope
// release), resolves its exclusive prefix by lookback (agent-scope acquire
// => cross-XCD L2 invalidate), then normalizes from registers. x is read
// once, y written once: ~256 MB of HBM traffic total (~41 us at 6.3 TB/s).
// Lookback chains follow ascending linear block IDs (chunk = blockIdx.x),
// matching dispatch issue order => no deadlock. Flags zeroed by init kernel
// (workspace arrives poisoned).

#define T_DIM 8192
#define B_DIM 8
#define D_DIM 512
#define BD    (B_DIM * D_DIM)   // 4096 floats per time row
#define BD4   (BD / 4)          // 1024 float4 per time row
#define D4    (D_DIM / 4)       // 128 float4 per (t,b)
#define C0    2.0f              // PRIOR_COUNT
#define EPS   1e-5f

#define NCF   512               // chunks for fused path
#define CTF   (T_DIM / NCF)     // 16 steps per chunk
#define NWF   (CTF / 8)         // mask words per chunk

// ---------------- flags init (ws arrives poisoned) ----------------
__global__ __launch_bounds__(256) void ts_init(int* __restrict__ flags) {
  flags[blockIdx.x * 256 + threadIdx.x] = 0;
}

// ---------------- fused single-pass kernel ----------------
__global__ __launch_bounds__(128) void ts_fused(
    const float* __restrict__ x, const unsigned char* __restrict__ mask,
    const float* __restrict__ pm, const float* __restrict__ plv,
    const float* __restrict__ w, const float* __restrict__ bias,
    float* __restrict__ agg1, float* __restrict__ agg2,
    float* __restrict__ aggc,
    float* __restrict__ pre1, float* __restrict__ pre2,
    float* __restrict__ prec,
    int* __restrict__ flags, float* __restrict__ out) {
  const int chunk = blockIdx.x;
  const int b     = blockIdx.y;
  const int tid   = threadIdx.x;
  const int t0    = chunk * CTF;
  const int col   = b * D4 + tid;
  const int fidx  = chunk * B_DIM + b;

  unsigned long long mw[NWF];
  const unsigned long long* m8 =
      (const unsigned long long*)(mask + b * T_DIM + t0);
#pragma unroll
  for (int j = 0; j < NWF; ++j) mw[j] = m8[j];

  // x slab into registers: read once, used twice (partials + epilogue).
  const float4* xp = (const float4*)x;
  float4 xv[CTF];
#pragma unroll
  for (int i = 0; i < CTF; ++i) xv[i] = xp[(t0 + i) * BD4 + col];

  float4 s1 = make_float4(0.f, 0.f, 0.f, 0.f);
  float4 s2 = make_float4(0.f, 0.f, 0.f, 0.f);
  float c = 0.f;
#pragma unroll
  for (int i = 0; i < CTF; ++i) {
    float valid = ((mw[i >> 3] >> ((i & 7) * 8)) & 0xffULL) ? 0.f : 1.f;
    float4 v = xv[i];
    c += valid;
    s1.x += valid * v.x; s2.x += valid * v.x * v.x;
    s1.y += valid * v.y; s2.y += valid * v.y * v.y;
    s1.z += valid * v.z; s2.z += valid * v.z * v.z;
    s1.w += valid * v.w; s2.w += valid * v.w * v.w;
  }

  const int pidx = chunk * BD4 + col;
  float4 R1 = make_float4(0.f, 0.f, 0.f, 0.f);  // exclusive prefix
  float4 R2 = make_float4(0.f, 0.f, 0.f, 0.f);
  float Rc = 0.f;

  if (chunk == 0) {
    ((float4*)pre1)[pidx] = s1;
    ((float4*)pre2)[pidx] = s2;
    if (tid == 0) prec[fidx] = c;
    __syncthreads();  // all block stores drained before release
    if (tid == 0)
      __hip_atomic_store(&flags[fidx], 2, __ATOMIC_RELEASE,
                         __HIP_MEMORY_SCOPE_AGENT);
  } else {
    // publish aggregate first so successors can make progress
    ((float4*)agg1)[pidx] = s1;
    ((float4*)agg2)[pidx] = s2;
    if (tid == 0) aggc[fidx] = c;
    __syncthreads();
    if (tid == 0)
      __hip_atomic_store(&flags[fidx], 1, __ATOMIC_RELEASE,
                         __HIP_MEMORY_SCOPE_AGENT);

    // decoupled lookback: walk predecessors until a full prefix is found
    __shared__ int sflag;
    int k = chunk - 1;
    for (;;) {
      if (tid == 0) {
        int st;
        do {
          st = __hip_atomic_load(&flags[k * B_DIM + b], __ATOMIC_RELAXED,
                                 __HIP_MEMORY_SCOPE_AGENT);
        } while (st == 0);
        // acquire reload: orders + invalidates stale L2 lines (cross-XCD)
        st = __hip_atomic_load(&flags[k * B_DIM + b], __ATOMIC_ACQUIRE,
                               __HIP_MEMORY_SCOPE_AGENT);
        sflag = st;
      }
      __syncthreads();           // sflag visible to all
      const int st = sflag;
      __syncthreads();           // safe to overwrite sflag next iter
      const int kidx = k * BD4 + col;
      if (st == 2) {
        float4 a = ((const float4*)pre1)[kidx];
        float4 d = ((const float4*)pre2)[kidx];
        R1.x += a.x; R1.y += a.y; R1.z += a.z; R1.w += a.w;
        R2.x += d.x; R2.y += d.y; R2.z += d.z; R2.w += d.w;
        Rc += prec[k * B_DIM + b];
        break;
      }
      float4 a = ((const float4*)agg1)[kidx];
      float4 d = ((const float4*)agg2)[kidx];
      R1.x += a.x; R1.y += a.y; R1.z += a.z; R1.w += a.w;
      R2.x += d.x; R2.y += d.y; R2.z += d.z; R2.w += d.w;
      Rc += aggc[k * B_DIM + b];
      --k;
    }

    // publish inclusive prefix (unblocks successors before our epilogue)
    float4 P1, P2;
    P1.x = R1.x + s1.x; P1.y = R1.y + s1.y;
    P1.z = R1.z + s1.z; P1.w = R1.w + s1.w;
    P2.x = R2.x + s2.x; P2.y = R2.y + s2.y;
    P2.z = R2.z + s2.z; P2.w = R2.w + s2.w;
    ((float4*)pre1)[pidx] = P1;
    ((float4*)pre2)[pidx] = P2;
    if (tid == 0) prec[fidx] = Rc + c;
    __syncthreads();
    if (tid == 0)
      __hip_atomic_store(&flags[fidx], 2, __ATOMIC_RELEASE,
                         __HIP_MEMORY_SCOPE_AGENT);
  }

  // ---------------- epilogue: normalize from registers ----------------
  float4 pm4 = ((const float4*)pm)[tid];
  float4 lv4 = ((const float4*)plv)[tid];
  float4 g4  = ((const float4*)w)[tid];
  float4 be4 = ((const float4*)bias)[tid];
  g4.x += 1.f; g4.y += 1.f; g4.z += 1.f; g4.w += 1.f;
  float M0x = C0 * pm4.x, M0y = C0 * pm4.y, M0z = C0 * pm4.z, M0w = C0 * pm4.w;
  float V2x = C0 * (__expf(lv4.x) + pm4.x * pm4.x);
  float V2y = C0 * (__expf(lv4.y) + pm4.y * pm4.y);
  float V2z = C0 * (__expf(lv4.z) + pm4.z * pm4.z);
  float V2w = C0 * (__expf(lv4.w) + pm4.w * pm4.w);

  float4 S1 = R1, S2 = R2;
  float c2 = C0 + Rc;
  float4* op = (float4*)out;

#pragma unroll
  for (int i = 0; i < CTF; ++i) {
    float valid = ((mw[i >> 3] >> ((i & 7) * 8)) & 0xffULL) ? 0.f : 1.f;
    float4 v = xv[i];
    c2 += valid;
    float rc = __builtin_amdgcn_rcpf(c2);
    float4 y;
    {
      S1.x += valid * v.x; S2.x += valid * v.x * v.x;
      float M = M0x + S1.x;
      float mean = M * rc;
      float var = (V2x + S2.x - M * M * rc) * rc;
      y.x = (v.x - mean) * __builtin_amdgcn_rsqf(var + EPS) * g4.x + be4.x;
    }
    {
      S1.y += valid * v.y; S2.y += valid * v.y * v.y;
      float M = M0y + S1.y;
      float mean = M * rc;
      float var = (V2y + S2.y - M * M * rc) * rc;
      y.y = (v.y - mean) * __builtin_amdgcn_rsqf(var + EPS) * g4.y + be4.y;
    }
    {
      S1.z += valid * v.z; S2.z += valid * v.z * v.z;
      float M = M0z + S1.z;
      float mean = M * rc;
      float var = (V2z + S2.z - M * M * rc) * rc;
      y.z = (v.z - mean) * __builtin_amdgcn_rsqf(var + EPS) * g4.z + be4.z;
    }
    {
      S1.w += valid * v.w; S2.w += valid * v.w * v.w;
      float M = M0w + S1.w;
      float mean = M * rc;
      float var = (V2w + S2.w - M * M * rc) * rc;
      y.w = (v.w - mean) * __builtin_amdgcn_rsqf(var + EPS) * g4.w + be4.w;
    }
    op[(t0 + i) * BD4 + col] = y;
  }
}

// ================= fallback path (v2 3-kernel, small ws) =================
__device__ __forceinline__ float4 f4add(float4 a, float4 b) {
  return make_float4(a.x + b.x, a.y + b.y, a.z + b.z, a.w + b.w);
}
__device__ __forceinline__ float4 f4sub(float4 a, float4 b) {
  return make_float4(a.x - b.x, a.y - b.y, a.z - b.z, a.w - b.w);
}

template <int NC>
__global__ __launch_bounds__(128) void ts_pass1(
    const float* __restrict__ x, const unsigned char* __restrict__ mask,
    float* __restrict__ s1p, float* __restrict__ s2p, float* __restrict__ cnt) {
  constexpr int CT = T_DIM / NC;
  constexpr int NW = CT / 8;
  const int chunk = blockIdx.x;
  const int b     = blockIdx.y;
  const int tid   = threadIdx.x;
  const int t0    = chunk * CT;
  const float4* xp = (const float4*)x;

  unsigned long long mw[NW];
  const unsigned long long* m8 =
      (const unsigned long long*)(mask + b * T_DIM + t0);
#pragma unroll
  for (int j = 0; j < NW; ++j) mw[j] = m8[j];

  float4 s1 = make_float4(0.f, 0.f, 0.f, 0.f);
  float4 s2 = make_float4(0.f, 0.f, 0.f, 0.f);
  float c = 0.f;
#pragma unroll 8
  for (int i = 0; i < CT; ++i) {
    float valid = ((mw[i >> 3] >> ((i & 7) * 8)) & 0xffULL) ? 0.f : 1.f;
    float4 v = xp[(t0 + i) * BD4 + b * D4 + tid];
    c += valid;
    s1.x += valid * v.x; s2.x += valid * v.x * v.x;
    s1.y += valid * v.y; s2.y += valid * v.y * v.y;
    s1.z += valid * v.z; s2.z += valid * v.z * v.z;
    s1.w += valid * v.w; s2.w += valid * v.w * v.w;
  }
  const int pidx = chunk * BD4 + b * D4 + tid;
  ((float4*)s1p)[pidx] = s1;
  ((float4*)s2p)[pidx] = s2;
  if (tid == 0) cnt[chunk * B_DIM + b] = c;
}

template <int NC>
__global__ __launch_bounds__(256) void ts_pass2(
    float* __restrict__ s1p, float* __restrict__ s2p, float* __restrict__ cnt) {
  constexpr int KPL = NC / 64;
  const int wid  = (blockIdx.x * 256 + threadIdx.x) >> 6;
  const int lane = threadIdx.x & 63;

  if (wid < 2 * BD4) {
    float4* base = (float4*)(wid < BD4 ? s1p : s2p);
    const int col = wid & (BD4 - 1);
    float4 vals[KPL];
#pragma unroll
    for (int j = 0; j < KPL; ++j)
      vals[j] = base[(lane * KPL + j) * BD4 + col];
#pragma unroll
    for (int j = 1; j < KPL; ++j) vals[j] = f4add(vals[j], vals[j - 1]);
    float4 tot = vals[KPL - 1];
    float4 inc = tot;
#pragma unroll
    for (int off = 1; off < 64; off <<= 1) {
      float4 o;
      o.x = __shfl_up(inc.x, off);
      o.y = __shfl_up(inc.y, off);
      o.z = __shfl_up(inc.z, off);
      o.w = __shfl_up(inc.w, off);
      if (lane >= off) inc = f4add(inc, o);
    }
    float4 excl = f4sub(inc, tot);
#pragma unroll
    for (int j = KPL - 1; j >= 1; --j)
      base[(lane * KPL + j) * BD4 + col] = f4add(excl, vals[j - 1]);
    base[(lane * KPL) * BD4 + col] = excl;
  } else if (wid < 2 * BD4 + B_DIM) {
    const int b = wid - 2 * BD4;
    float vals[KPL];
#pragma unroll
    for (int j = 0; j < KPL; ++j) vals[j] = cnt[(lane * KPL + j) * B_DIM + b];
#pragma unroll
    for (int j = 1; j < KPL; ++j) vals[j] += vals[j - 1];
    float tot = vals[KPL - 1];
    float inc = tot;
#pragma unroll
    for (int off = 1; off < 64; off <<= 1) {
      float o = __shfl_up(inc, off);
      if (lane >= off) inc += o;
    }
    float excl = inc - tot;
#pragma unroll
    for (int j = KPL - 1; j >= 1; --j)
      cnt[(lane * KPL + j) * B_DIM + b] = excl + vals[j - 1];
    cnt[lane * KPL * B_DIM + b] = excl;
  }
}

template <int NC>
__global__ __launch_bounds__(128) void ts_pass3(
    const float* __restrict__ x, const unsigned char* __restrict__ mask,
    const float* __restrict__ pm, const float* __restrict__ plv,
    const float* __restrict__ w, const float* __restrict__ bias,
    const float* __restrict__ e1, const float* __restrict__ e2,
    const float* __restrict__ ecnt, float* __restrict__ out) {
  constexpr int CT = T_DIM / NC;
  constexpr int NW = CT / 8;
  const int chunk = blockIdx.x;
  const int b     = blockIdx.y;
  const int tid   = threadIdx.x;
  const int t0    = chunk * CT;
  const int col   = b * D4 + tid;

  float4 S1 = ((const float4*)e1)[chunk * BD4 + col];
  float4 S2 = ((const float4*)e2)[chunk * BD4 + col];
  float c = C0 + ecnt[chunk * B_DIM + b];

  float4 pm4 = ((const float4*)pm)[tid];
  float4 lv4 = ((const float4*)plv)[tid];
  float4 g4  = ((const float4*)w)[tid];
  float4 be4 = ((const float4*)bias)[tid];
  g4.x += 1.f; g4.y += 1.f; g4.z += 1.f; g4.w += 1.f;
  float M0x = C0 * pm4.x, M0y = C0 * pm4.y, M0z = C0 * pm4.z, M0w = C0 * pm4.w;
  float V2x = C0 * (__expf(lv4.x) + pm4.x * pm4.x);
  float V2y = C0 * (__expf(lv4.y) + pm4.y * pm4.y);
  float V2z = C0 * (__expf(lv4.z) + pm4.z * pm4.z);
  float V2w = C0 * (__expf(lv4.w) + pm4.w * pm4.w);

  unsigned long long mw[NW];
  const unsigned long long* m8 =
      (const unsigned long long*)(mask + b * T_DIM + t0);
#pragma unroll
  for (int j = 0; j < NW; ++j) mw[j] = m8[j];

  const float4* xp = (const float4*)x;
  float4* op = (float4*)out;

#pragma unroll 4
  for (int i = 0; i < CT; ++i) {
    float valid = ((mw[i >> 3] >> ((i & 7) * 8)) & 0xffULL) ? 0.f : 1.f;
    const int xi = (t0 + i) * BD4 + col;
    float4 v = xp[xi];
    c += valid;
    float rc = __builtin_amdgcn_rcpf(c);
    float4 y;
    {
      S1.x += valid * v.x; S2.x += valid * v.x * v.x;
      float M = M0x + S1.x;
      float mean = M * rc;
      float var = (V2x + S2.x - M * M * rc) * rc;
      y.x = (v.x - mean) * __builtin_amdgcn_rsqf(var + EPS) * g4.x + be4.x;
    }
    {
      S1.y += valid * v.y; S2.y += valid * v.y * v.y;
      float M = M0y + S1.y;
      float mean = M * rc;
      float var = (V2y + S2.y - M * M * rc) * rc;
      y.y = (v.y - mean) * __builtin_amdgcn_rsqf(var + EPS) * g4.y + be4.y;
    }
    {
      S1.z += valid * v.z; S2.z += valid * v.z * v.z;
      float M = M0z + S1.z;
      float mean = M * rc;
      float var = (V2z + S2.z - M * M * rc) * rc;
      y.z = (v.z - mean) * __builtin_amdgcn_rsqf(var + EPS) * g4.z + be4.z;
    }
    {
      S1.w += valid * v.w; S2.w += valid * v.w * v.w;
      float M = M0w + S1.w;
      float mean = M * rc;
      float var = (V2w + S2.w - M * M * rc) * rc;
      y.w = (v.w - mean) * __builtin_amdgcn_rsqf(var + EPS) * g4.w + be4.w;
    }
    op[xi] = y;
  }
}

template <int NC>
static void run_3pass(const float* x, const unsigned char* mask,
                      const float* pm, const float* plv, const float* w,
                      const float* bias, float* out, float* ws,
                      hipStream_t stream) {
  float* s1p = ws;
  float* s2p = s1p + (size_t)NC * BD;
  float* cnt = s2p + (size_t)NC * BD;
  dim3 grid(NC, B_DIM);
  ts_pass1<NC><<<grid, 128, 0, stream>>>(x, mask, s1p, s2p, cnt);
  const int scan_waves = 2 * BD4 + B_DIM;
  const int scan_blocks = (scan_waves + 3) / 4;
  ts_pass2<NC><<<scan_blocks, 256, 0, stream>>>(s1p, s2p, cnt);
  ts_pass3<NC><<<grid, 128, 0, stream>>>(x, mask, pm, plv, w, bias, s1p, s2p,
                                         cnt, out);
}

// ---------------- launch ----------------
extern "C" void kernel_launch(void* const* d_in, const int* in_sizes, int n_in,
                              void* d_out, int out_size, void* d_ws,
                              size_t ws_size, hipStream_t stream) {
  const float* x    = (const float*)d_in[0];
  const float* pm   = (const float*)d_in[1];
  const float* plv  = (const float*)d_in[2];
  const float* w    = (const float*)d_in[3];
  const float* bias = (const float*)d_in[4];
  const unsigned char* mask = (const unsigned char*)d_in[5];
  float* out = (float*)d_out;
  float* ws  = (float*)d_ws;

  // fused ws: agg1,agg2,pre1,pre2 [NCF*BD] + aggc,prec [NCF*B] + flags
  const size_t fused_floats = (size_t)4 * NCF * BD + 2 * NCF * B_DIM;
  const size_t need_fused = fused_floats * sizeof(float) +
                            (size_t)NCF * B_DIM * sizeof(int);
  if (ws_size >= need_fused) {
    float* agg1 = ws;
    float* agg2 = agg1 + (size_t)NCF * BD;
    float* pre1 = agg2 + (size_t)NCF * BD;
    float* pre2 = pre1 + (size_t)NCF * BD;
    float* aggc = pre2 + (size_t)NCF * BD;
    float* prec = aggc + (size_t)NCF * B_DIM;
    int*   flags = (int*)(prec + (size_t)NCF * B_DIM);

    ts_init<<<(NCF * B_DIM) / 256, 256, 0, stream>>>(flags);
    dim3 grid(NCF, B_DIM);
    ts_fused<<<grid, 128, 0, stream>>>(x, mask, pm, plv, w, bias, agg1, agg2,
                                       aggc, pre1, pre2, prec, flags, out);
    return;
  }

  const size_t need512 = ((size_t)2 * 512 * BD + 512 * B_DIM) * sizeof(float);
  const size_t need256 = ((size_t)2 * 256 * BD + 256 * B_DIM) * sizeof(float);
  if (ws_size >= need512) {
    run_3pass<512>(x, mask, pm, plv, w, bias, out, ws, stream);
  } else if (ws_size >= need256) {
    run_3pass<256>(x, mask, pm, plv, w, bias, out, ws, stream);
  } else {
    run_3pass<128>(x, mask, pm, plv, w, bias, out, ws, stream);
  }
}

// Round 4
// 276.402 us; speedup vs baseline: 3.9367x; 3.9367x over previous
//
#include <hip/hip_runtime.h>
#include <math.h>

// TimestepNorm forward, prefix-sum reformulation:
//   c_t   = C0 + #valid<=t
//   M_t   = C0*pm + sum(valid*x)             -> mean = M/c
//   var_t = (V2 + sum(valid*x^2) - M_t^2/c_t)/c_t,  V2 = C0*(exp(plv)+pm^2)
//
// v5 = v4 with the nontemporal builtin type fixed: clang's
// __builtin_nontemporal_load/store rejects HIP_vector_type pointers, so the
// nt accesses go through a native ext_vector_type(4) float alias.
// Rationale (v4): 3-pass chunked scan (verified structure, 284.6 us) +
//   - pass3 y stores nontemporal (y never re-read; avoid write-allocate
//     evicting x from L2/L3 during pass3)
//   - pass3 x loads nontemporal (x dead after pass3)
// NC=512 => CT=16, 4096 blocks x 128 thr: 32 waves/CU potential.

#define T_DIM 8192
#define B_DIM 8
#define D_DIM 512
#define BD    (B_DIM * D_DIM)   // 4096 floats per time row
#define BD4   (BD / 4)          // 1024 float4 per time row
#define D4    (D_DIM / 4)       // 128 float4 per (t,b)
#define C0    2.0f              // PRIOR_COUNT
#define EPS   1e-5f

typedef float nt_f4 __attribute__((ext_vector_type(4)));

__device__ __forceinline__ float4 f4add(float4 a, float4 b) {
  return make_float4(a.x + b.x, a.y + b.y, a.z + b.z, a.w + b.w);
}
__device__ __forceinline__ float4 f4sub(float4 a, float4 b) {
  return make_float4(a.x - b.x, a.y - b.y, a.z - b.z, a.w - b.w);
}

__device__ __forceinline__ float4 ntload4(const float4* p) {
  nt_f4 v = __builtin_nontemporal_load((const nt_f4*)p);
  return make_float4(v.x, v.y, v.z, v.w);
}
__device__ __forceinline__ void ntstore4(float4 v, float4* p) {
  nt_f4 t = {v.x, v.y, v.z, v.w};
  __builtin_nontemporal_store(t, (nt_f4*)p);
}

// ---------------- pass1: per-chunk partial sums ----------------
template <int NC>
__global__ __launch_bounds__(128) void ts_pass1(
    const float* __restrict__ x, const unsigned char* __restrict__ mask,
    float* __restrict__ s1p, float* __restrict__ s2p, float* __restrict__ cnt) {
  constexpr int CT = T_DIM / NC;
  constexpr int NW = CT / 8;
  const int chunk = blockIdx.x;
  const int b     = blockIdx.y;
  const int tid   = threadIdx.x;
  const int t0    = chunk * CT;
  const float4* xp = (const float4*)x;

  unsigned long long mw[NW];
  const unsigned long long* m8 =
      (const unsigned long long*)(mask + b * T_DIM + t0);
#pragma unroll
  for (int j = 0; j < NW; ++j) mw[j] = m8[j];

  float4 s1 = make_float4(0.f, 0.f, 0.f, 0.f);
  float4 s2 = make_float4(0.f, 0.f, 0.f, 0.f);
  float c = 0.f;
#pragma unroll 8
  for (int i = 0; i < CT; ++i) {
    float valid = ((mw[i >> 3] >> ((i & 7) * 8)) & 0xffULL) ? 0.f : 1.f;
    float4 v = xp[(t0 + i) * BD4 + b * D4 + tid];
    c += valid;
    s1.x += valid * v.x; s2.x += valid * v.x * v.x;
    s1.y += valid * v.y; s2.y += valid * v.y * v.y;
    s1.z += valid * v.z; s2.z += valid * v.z * v.z;
    s1.w += valid * v.w; s2.w += valid * v.w * v.w;
  }
  const int pidx = chunk * BD4 + b * D4 + tid;
  ((float4*)s1p)[pidx] = s1;
  ((float4*)s2p)[pidx] = s2;
  if (tid == 0) cnt[chunk * B_DIM + b] = c;
}

// ---------------- pass2: wave-parallel exclusive scan over chunks ----------
// One wave per column. s1p/s2p: 2*BD4 float4-columns of length NC (stride BD4
// float4). cnt: B_DIM scalar columns of length NC (stride B_DIM). In-place:
// each column is owned by exactly one wave.
template <int NC>
__global__ __launch_bounds__(256) void ts_pass2(
    float* __restrict__ s1p, float* __restrict__ s2p, float* __restrict__ cnt) {
  constexpr int KPL = NC / 64;  // chunks per lane
  const int wid  = (blockIdx.x * 256 + threadIdx.x) >> 6;
  const int lane = threadIdx.x & 63;

  if (wid < 2 * BD4) {
    float4* base = (float4*)(wid < BD4 ? s1p : s2p);
    const int col = wid & (BD4 - 1);
    float4 vals[KPL];
#pragma unroll
    for (int j = 0; j < KPL; ++j)
      vals[j] = base[(lane * KPL + j) * BD4 + col];
#pragma unroll
    for (int j = 1; j < KPL; ++j) vals[j] = f4add(vals[j], vals[j - 1]);
    float4 tot = vals[KPL - 1];
    float4 inc = tot;
#pragma unroll
    for (int off = 1; off < 64; off <<= 1) {
      float4 o;
      o.x = __shfl_up(inc.x, off);
      o.y = __shfl_up(inc.y, off);
      o.z = __shfl_up(inc.z, off);
      o.w = __shfl_up(inc.w, off);
      if (lane >= off) inc = f4add(inc, o);
    }
    float4 excl = f4sub(inc, tot);  // exclusive prefix of this lane's segment
#pragma unroll
    for (int j = KPL - 1; j >= 1; --j)
      base[(lane * KPL + j) * BD4 + col] = f4add(excl, vals[j - 1]);
    base[(lane * KPL) * BD4 + col] = excl;
  } else if (wid < 2 * BD4 + B_DIM) {
    const int b = wid - 2 * BD4;
    float vals[KPL];
#pragma unroll
    for (int j = 0; j < KPL; ++j) vals[j] = cnt[(lane * KPL + j) * B_DIM + b];
#pragma unroll
    for (int j = 1; j < KPL; ++j) vals[j] += vals[j - 1];
    float tot = vals[KPL - 1];
    float inc = tot;
#pragma unroll
    for (int off = 1; off < 64; off <<= 1) {
      float o = __shfl_up(inc, off);
      if (lane >= off) inc += o;
    }
    float excl = inc - tot;
#pragma unroll
    for (int j = KPL - 1; j >= 1; --j)
      cnt[(lane * KPL + j) * B_DIM + b] = excl + vals[j - 1];
    cnt[lane * KPL * B_DIM + b] = excl;
  }
}

// ---------------- pass3: replay chunk with y epilogue ----------------
template <int NC>
__global__ __launch_bounds__(128) void ts_pass3(
    const float* __restrict__ x, const unsigned char* __restrict__ mask,
    const float* __restrict__ pm, const float* __restrict__ plv,
    const float* __restrict__ w, const float* __restrict__ bias,
    const float* __restrict__ e1, const float* __restrict__ e2,
    const float* __restrict__ ecnt, float* __restrict__ out) {
  constexpr int CT = T_DIM / NC;
  constexpr int NW = CT / 8;
  const int chunk = blockIdx.x;
  const int b     = blockIdx.y;
  const int tid   = threadIdx.x;
  const int t0    = chunk * CT;
  const int col   = b * D4 + tid;

  // Exclusive chunk prefix: O(1) loads (pass2 already scanned).
  float4 S1 = ((const float4*)e1)[chunk * BD4 + col];
  float4 S2 = ((const float4*)e2)[chunk * BD4 + col];
  float c = C0 + ecnt[chunk * B_DIM + b];

  float4 pm4 = ((const float4*)pm)[tid];
  float4 lv4 = ((const float4*)plv)[tid];
  float4 g4  = ((const float4*)w)[tid];
  float4 be4 = ((const float4*)bias)[tid];
  g4.x += 1.f; g4.y += 1.f; g4.z += 1.f; g4.w += 1.f;
  float M0x = C0 * pm4.x, M0y = C0 * pm4.y, M0z = C0 * pm4.z, M0w = C0 * pm4.w;
  float V2x = C0 * (__expf(lv4.x) + pm4.x * pm4.x);
  float V2y = C0 * (__expf(lv4.y) + pm4.y * pm4.y);
  float V2z = C0 * (__expf(lv4.z) + pm4.z * pm4.z);
  float V2w = C0 * (__expf(lv4.w) + pm4.w * pm4.w);

  unsigned long long mw[NW];
  const unsigned long long* m8 =
      (const unsigned long long*)(mask + b * T_DIM + t0);
#pragma unroll
  for (int j = 0; j < NW; ++j) mw[j] = m8[j];

  const float4* xp = (const float4*)x;
  float4* op = (float4*)out;

#pragma unroll 4
  for (int i = 0; i < CT; ++i) {
    float valid = ((mw[i >> 3] >> ((i & 7) * 8)) & 0xffULL) ? 0.f : 1.f;
    const int xi = (t0 + i) * BD4 + col;
    // x is dead after this kernel: nontemporal load (no cache pollution).
    float4 v = ntload4(&xp[xi]);
    c += valid;
    float rc = __builtin_amdgcn_rcpf(c);
    float4 y;
    {
      S1.x += valid * v.x; S2.x += valid * v.x * v.x;
      float M = M0x + S1.x;
      float mean = M * rc;
      float var = (V2x + S2.x - M * M * rc) * rc;
      y.x = (v.x - mean) * __builtin_amdgcn_rsqf(var + EPS) * g4.x + be4.x;
    }
    {
      S1.y += valid * v.y; S2.y += valid * v.y * v.y;
      float M = M0y + S1.y;
      float mean = M * rc;
      float var = (V2y + S2.y - M * M * rc) * rc;
      y.y = (v.y - mean) * __builtin_amdgcn_rsqf(var + EPS) * g4.y + be4.y;
    }
    {
      S1.z += valid * v.z; S2.z += valid * v.z * v.z;
      float M = M0z + S1.z;
      float mean = M * rc;
      float var = (V2z + S2.z - M * M * rc) * rc;
      y.z = (v.z - mean) * __builtin_amdgcn_rsqf(var + EPS) * g4.z + be4.z;
    }
    {
      S1.w += valid * v.w; S2.w += valid * v.w * v.w;
      float M = M0w + S1.w;
      float mean = M * rc;
      float var = (V2w + S2.w - M * M * rc) * rc;
      y.w = (v.w - mean) * __builtin_amdgcn_rsqf(var + EPS) * g4.w + be4.w;
    }
    // y never re-read: nontemporal store (don't evict x from caches).
    ntstore4(y, &op[xi]);
  }
}

// ---------------- launch ----------------
template <int NC>
static void run_3pass(const float* x, const unsigned char* mask,
                      const float* pm, const float* plv, const float* w,
                      const float* bias, float* out, float* ws,
                      hipStream_t stream) {
  float* s1p = ws;
  float* s2p = s1p + (size_t)NC * BD;
  float* cnt = s2p + (size_t)NC * BD;
  dim3 grid(NC, B_DIM);
  ts_pass1<NC><<<grid, 128, 0, stream>>>(x, mask, s1p, s2p, cnt);
  const int scan_waves = 2 * BD4 + B_DIM;        // 2056
  const int scan_blocks = (scan_waves + 3) / 4;  // 514 blocks of 4 waves
  ts_pass2<NC><<<scan_blocks, 256, 0, stream>>>(s1p, s2p, cnt);
  ts_pass3<NC><<<grid, 128, 0, stream>>>(x, mask, pm, plv, w, bias, s1p, s2p,
                                         cnt, out);
}

extern "C" void kernel_launch(void* const* d_in, const int* in_sizes, int n_in,
                              void* d_out, int out_size, void* d_ws,
                              size_t ws_size, hipStream_t stream) {
  const float* x    = (const float*)d_in[0];
  const float* pm   = (const float*)d_in[1];
  const float* plv  = (const float*)d_in[2];
  const float* w    = (const float*)d_in[3];
  const float* bias = (const float*)d_in[4];
  const unsigned char* mask = (const unsigned char*)d_in[5];
  float* out = (float*)d_out;
  float* ws  = (float*)d_ws;

  const size_t need512 = ((size_t)2 * 512 * BD + 512 * B_DIM) * sizeof(float);
  const size_t need256 = ((size_t)2 * 256 * BD + 256 * B_DIM) * sizeof(float);
  if (ws_size >= need512) {
    run_3pass<512>(x, mask, pm, plv, w, bias, out, ws, stream);
  } else if (ws_size >= need256) {
    run_3pass<256>(x, mask, pm, plv, w, bias, out, ws, stream);
  } else {
    run_3pass<128>(x, mask, pm, plv, w, bias, out, ws, stream);
  }
}